// Round 1
// baseline (459.017 us; speedup 1.0000x reference)
//
#include <hip/hip_runtime.h>
#include <hip/hip_bf16.h>

// Problem constants
#define BATCH 32
#define SRC 1024
#define SEQ 128
#define CTX 5
#define DM 512
// GEMM tiling
#define BM 64
#define BN 64
#define BK 32

// ---------------------------------------------------------------------------
// Kernel 1: py[b*SEQ+s][d] = sum_k yce[b,s,k] * P_w[k,d] + P_b[d]
//   yce row = concat of 5 G_emb rows (tokens yc[b, s*5+c]), K = 2560.
//   A is gathered row-major (k-contig within each 512 chunk); B row-major.
// ---------------------------------------------------------------------------
__global__ __launch_bounds__(256) void k_py(
    const int* __restrict__ yc, const float* __restrict__ G_emb,
    const float* __restrict__ P_w, const float* __restrict__ P_b,
    float* __restrict__ py)
{
    __shared__ float As[BK][BM + 4];
    __shared__ float Bs[BK][BN + 4];
    const int tid = threadIdx.x;
    const int m0 = blockIdx.y * BM;   // row in [0, 4096)
    const int n0 = blockIdx.x * BN;   // col in [0, 512)
    const int ty = tid >> 4, tx = tid & 15;
    const int rowA = tid >> 3, segA = tid & 7;    // A: 64 rows x 32 k, float4
    const int rowB = tid >> 4, segB = tid & 15;   // B: 32 k x 64 n, float4

    float acc[4][4] = {};

    for (int k0 = 0; k0 < CTX * DM; k0 += BK) {
        const int c = k0 >> 9;        // which context embedding chunk
        const int off = k0 & 511;     // offset inside the 512-wide chunk
        #pragma unroll
        for (int r = 0; r < 2; ++r) {
            const int m = m0 + rowA + r * 32;
            const int b = m >> 7, s = m & 127;
            const int tok = yc[b * (SEQ * CTX) + s * CTX + c];
            const float4 av = *(const float4*)(G_emb + (size_t)tok * DM + off + segA * 4);
            As[segA * 4 + 0][rowA + r * 32] = av.x;
            As[segA * 4 + 1][rowA + r * 32] = av.y;
            As[segA * 4 + 2][rowA + r * 32] = av.z;
            As[segA * 4 + 3][rowA + r * 32] = av.w;
        }
        #pragma unroll
        for (int r = 0; r < 2; ++r) {
            const float4 bv = *(const float4*)(P_w + (size_t)(k0 + rowB + r * 16) * DM + n0 + segB * 4);
            *(float4*)&Bs[rowB + r * 16][segB * 4] = bv;
        }
        __syncthreads();
        #pragma unroll
        for (int kk = 0; kk < BK; ++kk) {
            const float4 a4 = *(const float4*)&As[kk][ty * 4];
            const float4 b4 = *(const float4*)&Bs[kk][tx * 4];
            const float av[4] = {a4.x, a4.y, a4.z, a4.w};
            const float bv[4] = {b4.x, b4.y, b4.z, b4.w};
            #pragma unroll
            for (int i = 0; i < 4; ++i)
                #pragma unroll
                for (int j = 0; j < 4; ++j)
                    acc[i][j] = fmaf(av[i], bv[j], acc[i][j]);
        }
        __syncthreads();
    }

    const float4 bias = *(const float4*)(P_b + n0 + tx * 4);
    #pragma unroll
    for (int i = 0; i < 4; ++i) {
        const int m = m0 + ty * 4 + i;
        float4 o;
        o.x = acc[i][0] + bias.x;
        o.y = acc[i][1] + bias.y;
        o.z = acc[i][2] + bias.z;
        o.w = acc[i][3] + bias.w;
        *(float4*)(py + (size_t)m * DM + n0 + tx * 4) = o;
    }
}

// ---------------------------------------------------------------------------
// Kernel 2: scores[b][s][x] = dot(py[b,s,:], F_emb[x_tok[b,x],:]) + mask
//   Per-batch GEMM M=128(s), N=1024(x), K=512. Both operands k-contiguous.
//   Written pre-softmax into the `a` region of d_out.
// ---------------------------------------------------------------------------
__global__ __launch_bounds__(256) void k_scores(
    const float* __restrict__ py, const int* __restrict__ xsrc,
    const float* __restrict__ F_emb, float* __restrict__ a_out)
{
    __shared__ float As[BK][BM + 4];   // [k][s]
    __shared__ float Bs[BK][BN + 4];   // [k][x]
    const int tid = threadIdx.x;
    const int bz = blockIdx.z;
    const int s0 = blockIdx.y * BM;    // 0 or 64
    const int x0 = blockIdx.x * BN;    // 0..960
    const int ty = tid >> 4, tx = tid & 15;
    const int rowA = tid >> 3, segA = tid & 7;

    const float* Ab = py + (size_t)bz * SEQ * DM;
    const int* xb = xsrc + (size_t)bz * SRC;

    float acc[4][4] = {};

    for (int k0 = 0; k0 < DM; k0 += BK) {
        #pragma unroll
        for (int r = 0; r < 2; ++r) {
            const int s = s0 + rowA + r * 32;
            const float4 av = *(const float4*)(Ab + (size_t)s * DM + k0 + segA * 4);
            As[segA * 4 + 0][rowA + r * 32] = av.x;
            As[segA * 4 + 1][rowA + r * 32] = av.y;
            As[segA * 4 + 2][rowA + r * 32] = av.z;
            As[segA * 4 + 3][rowA + r * 32] = av.w;
        }
        #pragma unroll
        for (int r = 0; r < 2; ++r) {
            const int tok = xb[x0 + rowA + r * 32];
            const float4 bv = *(const float4*)(F_emb + (size_t)tok * DM + k0 + segA * 4);
            Bs[segA * 4 + 0][rowA + r * 32] = bv.x;
            Bs[segA * 4 + 1][rowA + r * 32] = bv.y;
            Bs[segA * 4 + 2][rowA + r * 32] = bv.z;
            Bs[segA * 4 + 3][rowA + r * 32] = bv.w;
        }
        __syncthreads();
        #pragma unroll
        for (int kk = 0; kk < BK; ++kk) {
            const float4 a4 = *(const float4*)&As[kk][ty * 4];
            const float4 b4 = *(const float4*)&Bs[kk][tx * 4];
            const float av[4] = {a4.x, a4.y, a4.z, a4.w};
            const float bv[4] = {b4.x, b4.y, b4.z, b4.w};
            #pragma unroll
            for (int i = 0; i < 4; ++i)
                #pragma unroll
                for (int j = 0; j < 4; ++j)
                    acc[i][j] = fmaf(av[i], bv[j], acc[i][j]);
        }
        __syncthreads();
    }

    // padding mask: source token == 0 -> add -1e9 to that column
    float msk[4];
    #pragma unroll
    for (int j = 0; j < 4; ++j)
        msk[j] = (xb[x0 + tx * 4 + j] == 0) ? -1e9f : 0.0f;

    #pragma unroll
    for (int i = 0; i < 4; ++i) {
        const int s = s0 + ty * 4 + i;
        float4 o;
        o.x = acc[i][0] + msk[0];
        o.y = acc[i][1] + msk[1];
        o.z = acc[i][2] + msk[2];
        o.w = acc[i][3] + msk[3];
        *(float4*)(a_out + ((size_t)bz * SEQ + s) * SRC + x0 + tx * 4) = o;
    }
}

// ---------------------------------------------------------------------------
// Kernel 3: in-place softmax over last dim (1024) of a [4096 rows]
// ---------------------------------------------------------------------------
__global__ __launch_bounds__(256) void k_softmax(float* __restrict__ a)
{
    const int row = blockIdx.x;
    float* p = a + (size_t)row * SRC;
    const int tid = threadIdx.x;
    const int wave = tid >> 6, lane = tid & 63;

    float4 v = *(const float4*)(p + tid * 4);

    float mx = fmaxf(fmaxf(v.x, v.y), fmaxf(v.z, v.w));
    #pragma unroll
    for (int off = 32; off > 0; off >>= 1)
        mx = fmaxf(mx, __shfl_down(mx, off, 64));
    __shared__ float redm[4];
    if (lane == 0) redm[wave] = mx;
    __syncthreads();
    mx = fmaxf(fmaxf(redm[0], redm[1]), fmaxf(redm[2], redm[3]));

    const float e0 = __expf(v.x - mx);
    const float e1 = __expf(v.y - mx);
    const float e2 = __expf(v.z - mx);
    const float e3 = __expf(v.w - mx);

    float sm = e0 + e1 + e2 + e3;
    #pragma unroll
    for (int off = 32; off > 0; off >>= 1)
        sm += __shfl_down(sm, off, 64);
    __shared__ float reds[4];
    if (lane == 0) reds[wave] = sm;
    __syncthreads();
    sm = reds[0] + reds[1] + reds[2] + reds[3];

    const float inv = 1.0f / sm;
    float4 o;
    o.x = e0 * inv; o.y = e1 * inv; o.z = e2 * inv; o.w = e3 * inv;
    *(float4*)(p + tid * 4) = o;
}

// ---------------------------------------------------------------------------
// Kernel 4: out[b][s][d] = sum_x a[b,s,x] * F_emb[x_tok[b,x], d]
//   Per-batch GEMM M=128(s), N=512(d), K=1024(x). A k-contig, B n-contig.
// ---------------------------------------------------------------------------
__global__ __launch_bounds__(256) void k_out(
    const float* __restrict__ a, const int* __restrict__ xsrc,
    const float* __restrict__ F_emb, float* __restrict__ outp)
{
    __shared__ float As[BK][BM + 4];   // [k(=x)][s]
    __shared__ float Bs[BK][BN + 4];   // [k(=x)][d]
    const int tid = threadIdx.x;
    const int bz = blockIdx.z;
    const int s0 = blockIdx.y * BM;
    const int n0 = blockIdx.x * BN;
    const int ty = tid >> 4, tx = tid & 15;
    const int rowA = tid >> 3, segA = tid & 7;
    const int rowB = tid >> 4, segB = tid & 15;

    const float* Ab = a + (size_t)bz * SEQ * SRC;
    const int* xb = xsrc + (size_t)bz * SRC;

    float acc[4][4] = {};

    for (int k0 = 0; k0 < SRC; k0 += BK) {
        #pragma unroll
        for (int r = 0; r < 2; ++r) {
            const int s = s0 + rowA + r * 32;
            const float4 av = *(const float4*)(Ab + (size_t)s * SRC + k0 + segA * 4);
            As[segA * 4 + 0][rowA + r * 32] = av.x;
            As[segA * 4 + 1][rowA + r * 32] = av.y;
            As[segA * 4 + 2][rowA + r * 32] = av.z;
            As[segA * 4 + 3][rowA + r * 32] = av.w;
        }
        #pragma unroll
        for (int r = 0; r < 2; ++r) {
            const int tok = xb[k0 + rowB + r * 16];
            const float4 bv = *(const float4*)(F_emb + (size_t)tok * DM + n0 + segB * 4);
            *(float4*)&Bs[rowB + r * 16][segB * 4] = bv;
        }
        __syncthreads();
        #pragma unroll
        for (int kk = 0; kk < BK; ++kk) {
            const float4 a4 = *(const float4*)&As[kk][ty * 4];
            const float4 b4 = *(const float4*)&Bs[kk][tx * 4];
            const float av[4] = {a4.x, a4.y, a4.z, a4.w};
            const float bv[4] = {b4.x, b4.y, b4.z, b4.w};
            #pragma unroll
            for (int i = 0; i < 4; ++i)
                #pragma unroll
                for (int j = 0; j < 4; ++j)
                    acc[i][j] = fmaf(av[i], bv[j], acc[i][j]);
        }
        __syncthreads();
    }

    #pragma unroll
    for (int i = 0; i < 4; ++i) {
        const int s = s0 + ty * 4 + i;
        float4 o;
        o.x = acc[i][0]; o.y = acc[i][1]; o.z = acc[i][2]; o.w = acc[i][3];
        *(float4*)(outp + ((size_t)bz * SEQ + s) * DM + n0 + tx * 4) = o;
    }
}

// ---------------------------------------------------------------------------
extern "C" void kernel_launch(void* const* d_in, const int* in_sizes, int n_in,
                              void* d_out, int out_size, void* d_ws, size_t ws_size,
                              hipStream_t stream)
{
    const int*   x    = (const int*)d_in[0];    // [32,1024]
    const int*   yc   = (const int*)d_in[1];    // [32,640]
    const float* Femb = (const float*)d_in[2];  // [32000,512]
    const float* Gemb = (const float*)d_in[3];  // [32000,512]
    const float* Pw   = (const float*)d_in[4];  // [2560,512]
    const float* Pb   = (const float*)d_in[5];  // [512]

    float* out_p = (float*)d_out;                              // [32,128,512]
    float* a_p   = out_p + (size_t)BATCH * SEQ * DM;           // [32,128,1024]
    float* py_p  = (float*)d_ws;                               // [4096,512] = 8 MB

    dim3 blk(256);
    // py = yce @ P_w + P_b : M=4096, N=512, K=2560
    k_py<<<dim3(DM / BN, (BATCH * SEQ) / BM), blk, 0, stream>>>(yc, Gemb, Pw, Pb, py_p);
    // scores (pre-softmax) into a region: per-batch M=128, N=1024, K=512
    k_scores<<<dim3(SRC / BN, SEQ / BM, BATCH), blk, 0, stream>>>(py_p, x, Femb, a_p);
    // in-place softmax over SRC
    k_softmax<<<dim3(BATCH * SEQ), blk, 0, stream>>>(a_p);
    // out = a @ xe : per-batch M=128, N=512, K=1024
    k_out<<<dim3(DM / BN, SEQ / BM, BATCH), blk, 0, stream>>>(a_p, x, Femb, out_p);
}

// Round 2
// 278.381 us; speedup vs baseline: 1.6489x; 1.6489x over previous
//
#include <hip/hip_runtime.h>
#include <hip/hip_bf16.h>
#include <stdint.h>

#define BATCH 32
#define SRCN 1024
#define SEQL 128
#define CTXN 5
#define DMOD 512

typedef __attribute__((ext_vector_type(8))) short short8;
typedef __attribute__((ext_vector_type(4))) float floatx4;

typedef __attribute__((address_space(3))) void lds_t;
typedef __attribute__((address_space(1))) void glb_t;

__device__ __forceinline__ void gload_lds16(const void* g, void* l) {
    __builtin_amdgcn_global_load_lds((const glb_t*)g, (lds_t*)l, 16, 0, 0);
}

__device__ __forceinline__ ushort f2b(float f) {
    __hip_bfloat16 h = __float2bfloat16(f);
    return *reinterpret_cast<ushort*>(&h);
}

// ---------------------------------------------------------------------------
// Prep 1: gather+convert yce[4096][2560] bf16 (5 G_emb rows per (b,s))
// ---------------------------------------------------------------------------
__global__ __launch_bounds__(256) void k_yce(
    const int* __restrict__ yc, const float* __restrict__ G,
    ushort* __restrict__ yce)
{
    const int r = blockIdx.x;            // 0..4095 = b*128+s
    const int b = r >> 7, s = r & 127;
    const int tid = threadIdx.x;
    for (int i = tid; i < 640; i += 256) {
        const int c = i >> 7;            // context slot 0..4
        const int tok = yc[b * (SEQL * CTXN) + s * CTXN + c];
        const float4 v = *(const float4*)(G + (size_t)tok * DMOD + (i & 127) * 4);
        ushort4 o;
        o.x = f2b(v.x); o.y = f2b(v.y); o.z = f2b(v.z); o.w = f2b(v.w);
        *(ushort4*)(yce + (size_t)r * 2560 + i * 4) = o;
    }
}

// ---------------------------------------------------------------------------
// Prep 2: transpose+convert P_w [2560][512] f32 -> Pwt [512][2560] bf16
// ---------------------------------------------------------------------------
__global__ __launch_bounds__(256) void k_pwt(
    const float* __restrict__ Pw, ushort* __restrict__ Pwt)
{
    __shared__ float t[64][68];
    const int k0 = blockIdx.x * 64, n0 = blockIdx.y * 64;
    const int tid = threadIdx.x;
    #pragma unroll
    for (int it = 0; it < 4; ++it) {
        const int c = tid + it * 256;
        const int kr = c >> 4, c4 = c & 15;
        const float4 v = *(const float4*)(Pw + (size_t)(k0 + kr) * DMOD + n0 + c4 * 4);
        t[kr][c4 * 4 + 0] = v.x; t[kr][c4 * 4 + 1] = v.y;
        t[kr][c4 * 4 + 2] = v.z; t[kr][c4 * 4 + 3] = v.w;
    }
    __syncthreads();
    #pragma unroll
    for (int it = 0; it < 2; ++it) {
        const int c = tid + it * 256;
        const int n = c >> 3, seg = c & 7;
        ushort4 o0, o1;
        o0.x = f2b(t[seg * 8 + 0][n]); o0.y = f2b(t[seg * 8 + 1][n]);
        o0.z = f2b(t[seg * 8 + 2][n]); o0.w = f2b(t[seg * 8 + 3][n]);
        o1.x = f2b(t[seg * 8 + 4][n]); o1.y = f2b(t[seg * 8 + 5][n]);
        o1.z = f2b(t[seg * 8 + 6][n]); o1.w = f2b(t[seg * 8 + 7][n]);
        ushort* dst = Pwt + (size_t)(n0 + n) * 2560 + k0 + seg * 8;
        *(ushort4*)dst = o0; *(ushort4*)(dst + 4) = o1;
    }
}

// ---------------------------------------------------------------------------
// Prep 3: gather+convert xe[32*1024][512] bf16 (F_emb rows per source token)
// ---------------------------------------------------------------------------
__global__ __launch_bounds__(256) void k_xe(
    const int* __restrict__ x, const float* __restrict__ F,
    ushort* __restrict__ xe)
{
    const int r = blockIdx.x * 4 + (threadIdx.x >> 6);
    const int lane = threadIdx.x & 63;
    const int tok = x[r];
    const float4 v0 = *(const float4*)(F + (size_t)tok * DMOD + lane * 8);
    const float4 v1 = *(const float4*)(F + (size_t)tok * DMOD + lane * 8 + 4);
    ushort4 o0, o1;
    o0.x = f2b(v0.x); o0.y = f2b(v0.y); o0.z = f2b(v0.z); o0.w = f2b(v0.w);
    o1.x = f2b(v1.x); o1.y = f2b(v1.y); o1.z = f2b(v1.z); o1.w = f2b(v1.w);
    ushort* dst = xe + (size_t)r * DMOD + lane * 8;
    *(ushort4*)dst = o0; *(ushort4*)(dst + 4) = o1;
}

// ---------------------------------------------------------------------------
// Prep 4: per-batch transpose xe [1024][512] -> xet [512][1024] (bf16)
// ---------------------------------------------------------------------------
__global__ __launch_bounds__(256) void k_xet(
    const ushort* __restrict__ xe, ushort* __restrict__ xet)
{
    __shared__ ushort t[64][72];
    const int z = blockIdx.z;
    const int x0 = blockIdx.x * 64, d0 = blockIdx.y * 64;
    const ushort* in = xe + (size_t)z * SRCN * DMOD;
    ushort* out = xet + (size_t)z * DMOD * SRCN;
    const int tid = threadIdx.x;
    #pragma unroll
    for (int it = 0; it < 2; ++it) {
        const int c = tid + it * 256;
        const int xr = c >> 3, seg = c & 7;
        const uint4 v = *(const uint4*)(in + (size_t)(x0 + xr) * DMOD + d0 + seg * 8);
        *(uint4*)&t[xr][seg * 8] = v;
    }
    __syncthreads();
    #pragma unroll
    for (int it = 0; it < 2; ++it) {
        const int c = tid + it * 256;
        const int d = c >> 3, seg = c & 7;
        ushort4 o0, o1;
        o0.x = t[seg * 8 + 0][d]; o0.y = t[seg * 8 + 1][d];
        o0.z = t[seg * 8 + 2][d]; o0.w = t[seg * 8 + 3][d];
        o1.x = t[seg * 8 + 4][d]; o1.y = t[seg * 8 + 5][d];
        o1.z = t[seg * 8 + 6][d]; o1.w = t[seg * 8 + 7][d];
        ushort* dst = out + (size_t)(d0 + d) * SRCN + x0 + seg * 8;
        *(ushort4*)dst = o0; *(ushort4*)(dst + 4) = o1;
    }
}

// ---------------------------------------------------------------------------
// Unified MFMA GEMM: C[m][n] = sum_k A[m][k]*B[n][k]  (both bf16 k-contig)
// BM=128, BN=64, BK=64. 4 waves: 2x2 grid, each 64x32.
// LDS layout As[kc][m][8] (kc=k/8), Bs[kc][n][8] -> conflict-free b128 reads,
// staged via global_load_lds dwordx4 (wave-uniform dest base + lane*16).
// ---------------------------------------------------------------------------
template<bool BIAS, bool OUT_BF16>
__global__ __launch_bounds__(256) void k_gemm(
    const ushort* __restrict__ A, const ushort* __restrict__ B,
    const float* __restrict__ bias, void* __restrict__ Cout,
    int K, int lda, int ldb, int ldc,
    long long sA, long long sB, long long sC)
{
    __shared__ ushort As[128 * 64];   // elem idx = kc*1024 + m*8 + j
    __shared__ ushort Bs[64 * 64];    // elem idx = kc*512  + n*8 + j
    const int tid = threadIdx.x;
    const int w = tid >> 6, lane = tid & 63;
    const int l15 = lane & 15, q = lane >> 4;
    const int z = blockIdx.z;
    const int m0 = blockIdx.y * 128;
    const int n0 = blockIdx.x * 64;
    const ushort* Ab = A + (size_t)z * sA;
    const ushort* Bb = B + (size_t)z * sB;
    const int wm = w >> 1, wn = w & 1;

    floatx4 acc[4][2];
    #pragma unroll
    for (int mi = 0; mi < 4; ++mi)
        #pragma unroll
        for (int ni = 0; ni < 2; ++ni)
            acc[mi][ni] = (floatx4){0.f, 0.f, 0.f, 0.f};

    for (int k0 = 0; k0 < K; k0 += 64) {
        __syncthreads();   // previous iter's LDS reads complete
        // A tile: 16 chunks of 1KB; wave w takes cc = w*4..w*4+3
        #pragma unroll
        for (int i = 0; i < 4; ++i) {
            const int cc = w * 4 + i;
            const int kc = cc >> 1, mh = cc & 1;
            const int m = mh * 64 + lane;
            gload_lds16(Ab + (size_t)(m0 + m) * lda + k0 + kc * 8,
                        (void*)(As + cc * 512));
        }
        // B tile: 8 chunks; wave w takes kc = w*2..w*2+1
        #pragma unroll
        for (int i = 0; i < 2; ++i) {
            const int kc = w * 2 + i;
            gload_lds16(Bb + (size_t)(n0 + lane) * ldb + k0 + kc * 8,
                        (void*)(Bs + kc * 512));
        }
        __syncthreads();   // drains vmcnt -> LDS data ready
        #pragma unroll
        for (int s = 0; s < 2; ++s) {
            const int kc = s * 4 + q;
            short8 af[4], bf[2];
            #pragma unroll
            for (int mi = 0; mi < 4; ++mi)
                af[mi] = *(const short8*)(As + kc * 1024 + (wm * 64 + mi * 16 + l15) * 8);
            #pragma unroll
            for (int ni = 0; ni < 2; ++ni)
                bf[ni] = *(const short8*)(Bs + kc * 512 + (wn * 32 + ni * 16 + l15) * 8);
            #pragma unroll
            for (int mi = 0; mi < 4; ++mi)
                #pragma unroll
                for (int ni = 0; ni < 2; ++ni)
                    acc[mi][ni] = __builtin_amdgcn_mfma_f32_16x16x32_bf16(
                        af[mi], bf[ni], acc[mi][ni], 0, 0, 0);
        }
    }

    // Epilogue: C/D layout col=lane&15, row=q*4+reg
    #pragma unroll
    for (int ni = 0; ni < 2; ++ni) {
        const int col = n0 + wn * 32 + ni * 16 + l15;
        const float bv = BIAS ? bias[col] : 0.0f;
        #pragma unroll
        for (int mi = 0; mi < 4; ++mi) {
            const int row0 = m0 + wm * 64 + mi * 16 + q * 4;
            #pragma unroll
            for (int r = 0; r < 4; ++r) {
                const float v = acc[mi][ni][r] + bv;
                if (OUT_BF16)
                    ((ushort*)Cout + (size_t)z * sC)[(size_t)(row0 + r) * ldc + col] = f2b(v);
                else
                    ((float*)Cout + (size_t)z * sC)[(size_t)(row0 + r) * ldc + col] = v;
            }
        }
    }
}

// ---------------------------------------------------------------------------
// Softmax: mask (x==0 -> -1e9) + row softmax over 1024; writes fp32 a (d_out)
// in place and bf16 copy for GEMM3.
// ---------------------------------------------------------------------------
__global__ __launch_bounds__(256) void k_softmax(
    float* __restrict__ a, const int* __restrict__ x, ushort* __restrict__ abf)
{
    const int row = blockIdx.x;          // b*128+s
    const int b = row >> 7;
    float* p = a + (size_t)row * SRCN;
    ushort* pb = abf + (size_t)row * SRCN;
    const int tid = threadIdx.x;
    const int wave = tid >> 6, lane = tid & 63;

    float4 v = *(const float4*)(p + tid * 4);
    const int4 tk = *(const int4*)(x + (size_t)b * SRCN + tid * 4);
    if (tk.x == 0) v.x += -1e9f;
    if (tk.y == 0) v.y += -1e9f;
    if (tk.z == 0) v.z += -1e9f;
    if (tk.w == 0) v.w += -1e9f;

    float mx = fmaxf(fmaxf(v.x, v.y), fmaxf(v.z, v.w));
    #pragma unroll
    for (int off = 32; off > 0; off >>= 1)
        mx = fmaxf(mx, __shfl_down(mx, off, 64));
    __shared__ float redm[4];
    if (lane == 0) redm[wave] = mx;
    __syncthreads();
    mx = fmaxf(fmaxf(redm[0], redm[1]), fmaxf(redm[2], redm[3]));

    const float e0 = __expf(v.x - mx);
    const float e1 = __expf(v.y - mx);
    const float e2 = __expf(v.z - mx);
    const float e3 = __expf(v.w - mx);

    float sm = e0 + e1 + e2 + e3;
    #pragma unroll
    for (int off = 32; off > 0; off >>= 1)
        sm += __shfl_down(sm, off, 64);
    __shared__ float reds[4];
    if (lane == 0) reds[wave] = sm;
    __syncthreads();
    sm = reds[0] + reds[1] + reds[2] + reds[3];

    const float inv = 1.0f / sm;
    float4 o;
    o.x = e0 * inv; o.y = e1 * inv; o.z = e2 * inv; o.w = e3 * inv;
    *(float4*)(p + tid * 4) = o;
    ushort4 ob;
    ob.x = f2b(o.x); ob.y = f2b(o.y); ob.z = f2b(o.z); ob.w = f2b(o.w);
    *(ushort4*)(pb + tid * 4) = ob;
}

// ---------------------------------------------------------------------------
extern "C" void kernel_launch(void* const* d_in, const int* in_sizes, int n_in,
                              void* d_out, int out_size, void* d_ws, size_t ws_size,
                              hipStream_t stream)
{
    const int*   x    = (const int*)d_in[0];    // [32,1024]
    const int*   yc   = (const int*)d_in[1];    // [32,640]
    const float* Femb = (const float*)d_in[2];  // [32000,512]
    const float* Gemb = (const float*)d_in[3];  // [32000,512]
    const float* Pw   = (const float*)d_in[4];  // [2560,512]
    const float* Pb   = (const float*)d_in[5];  // [512]

    float* out_p = (float*)d_out;                         // [32,128,512]
    float* a_p   = out_p + (size_t)BATCH * SEQL * DMOD;   // [32,128,1024]

    char* ws = (char*)d_ws;
    ushort* yce  = (ushort*)(ws);                         // 4096*2560*2  = 20.97 MB
    ushort* pwt  = (ushort*)(ws + 20971520);              //  512*2560*2  =  2.62 MB
    ushort* xe   = (ushort*)(ws + 23592960);              // 32768*512*2  = 33.55 MB
    ushort* xet  = (ushort*)(ws + 57147392);              // 32*512*1024*2= 33.55 MB
    ushort* py   = (ushort*)(ws + 90701824);              // 4096*512*2   =  4.19 MB
    ushort* abf  = (ushort*)(ws + 94896128);              // 4096*1024*2  =  8.39 MB
                                                          // total 103.3 MB

    dim3 blk(256);
    k_yce<<<dim3(4096), blk, 0, stream>>>(yc, Gemb, yce);
    k_pwt<<<dim3(40, 8), blk, 0, stream>>>(Pw, pwt);
    k_xe<<<dim3(8192), blk, 0, stream>>>(x, Femb, xe);
    k_xet<<<dim3(16, 8, 32), blk, 0, stream>>>(xe, xet);

    // GEMM1: py[4096][512] = yce @ PwT + bias  (K=2560), bf16 out
    k_gemm<true, true><<<dim3(8, 32, 1), blk, 0, stream>>>(
        yce, pwt, Pb, py, 2560, 2560, 2560, DMOD, 0, 0, 0);
    // GEMM2: scores[b][128][1024] = py_b @ xe_b^T (K=512), fp32 into a region
    k_gemm<false, false><<<dim3(16, 1, BATCH), blk, 0, stream>>>(
        py, xe, nullptr, a_p, DMOD, DMOD, DMOD, SRCN,
        (long long)SEQL * DMOD, (long long)SRCN * DMOD, (long long)SEQL * SRCN);
    // mask + softmax (in place) + bf16 copy
    k_softmax<<<dim3(4096), blk, 0, stream>>>(a_p, x, abf);
    // GEMM3: out[b][128][512] = a_b @ xet_b^T (K=1024), fp32
    k_gemm<false, false><<<dim3(8, 1, BATCH), blk, 0, stream>>>(
        abf, xet, nullptr, out_p, SRCN, SRCN, SRCN, DMOD,
        (long long)SEQL * SRCN, (long long)DMOD * SRCN, (long long)SEQL * DMOD);
}